// Round 12
// baseline (210.806 us; speedup 1.0000x reference)
//
#include <hip/hip_runtime.h>
#include <hip/hip_bf16.h>

typedef unsigned int u32;
typedef unsigned short u16;

typedef __attribute__((ext_vector_type(8))) short bf16x8;
typedef __attribute__((ext_vector_type(4))) float f32x4;
typedef __attribute__((ext_vector_type(2))) float f32x2;

// ---------- bf16 helpers ----------
__device__ __forceinline__ float bflo(u32 p){ union{u32 u; float f;} v; v.u = p << 16; return v.f; }
__device__ __forceinline__ float bfhi(u32 p){ union{u32 u; float f;} v; v.u = p & 0xFFFF0000u; return v.f; }
__device__ __forceinline__ u16 f2bf(float f){
    union{float f; u32 u;} v; v.f = f;
    u32 r = (v.u + 0x7FFFu + ((v.u >> 16) & 1u)) >> 16;
    return (u16)r;
}
__device__ __forceinline__ u32 pack2(float a, float b){
    return ((u32)f2bf(a)) | (((u32)f2bf(b)) << 16);
}

#define HH 16
#define CC 32
#define HC 512   // H*C
#define KIN 128
#define CT 1056  // 512 + 512 + 32 output cols
#define RESCALE_THR 8.0f

// ---------- K_prep: fused {x->bf16, W->frag-order bf16, edge count} ----------
// counts must be zeroed (hipMemsetAsync) before this kernel.
__global__ __launch_bounds__(256) void k_prep(
    const float* __restrict__ x, const float* __restrict__ Wl,
    const float* __restrict__ Wr, const float* __restrict__ Wres,
    const int* __restrict__ ei,
    u16* __restrict__ xb, u16* __restrict__ wbt_frag, int* __restrict__ counts,
    int xq, int E, int N)
{
    int t = blockIdx.x * 256 + threadIdx.x;
    if (t < xq) {
        const float4* src = (const float4*)(x + (size_t)t * 8);
        float4 a = src[0], b = src[1];
        uint4 o;
        o.x = pack2(a.x, a.y); o.y = pack2(a.z, a.w);
        o.z = pack2(b.x, b.y); o.w = pack2(b.z, b.w);
        ((uint4*)xb)[t] = o;
    } else if (t < xq + CT * 128) {
        int u = t - xq;
        int c = u >> 7;            // 0..1055
        int k = u & 127;           // 0..127
        float v;
        if (c < 512)       v = Wl[(size_t)k * 512 + c];
        else if (c < 1024) v = Wr[(size_t)k * 512 + (c - 512)];
        else               v = Wres[(size_t)k * 32 + (c - 1024)];
        int e    = k & 7;
        int krow = k >> 3;
        int kk   = krow >> 2;
        int lane = ((krow & 3) << 4) | (c & 15);
        int ct   = c >> 4;
        wbt_frag[(((size_t)ct * 4 + kk) * 64 + lane) * 8 + e] = f2bf(v);
    } else if (t < xq + CT * 128 + E + N) {
        int e = t - xq - CT * 128;
        int dst = (e < E) ? ei[E + e] : e - E;
        atomicAdd(&counts[dst], 1);
    }
}

// ---------- K_mfma: [M,128] x [128,1056] via mfma_f32_16x16x32_bf16 ----------
__global__ __launch_bounds__(256) void k_mfma(
    const u16* __restrict__ xb, const u16* __restrict__ wbt_frag,
    u16* __restrict__ xl, u16* __restrict__ xr, float* __restrict__ xres,
    int N, int nrb)
{
    __shared__ u16 sh[128 * 128];   // 32 KB: A stage, then C stage
    const int i = blockIdx.x;
    const int xcd = i & 7;
    const int j = i >> 3;
    const int rb = xcd + 8 * (j / 9);
    const int cb = j % 9;
    if (rb >= nrb) return;
    const int tid = threadIdx.x;
    const int wave = tid >> 6, lane = tid & 63;
    const int row0 = rb * 128;

    uint4 zero = {0, 0, 0, 0};
    #pragma unroll
    for (int it = 0; it < 8; it++) {
        int idx = tid + it * 256;        // 0..2047
        int r = idx >> 4, ch = idx & 15;
        int grow = row0 + r;
        uint4 v = (grow < N) ? ((const uint4*)(xb + (size_t)grow * KIN))[ch] : zero;
        *(uint4*)(sh + r * 128 + ((ch ^ (r & 7)) * 8)) = v;
    }
    __syncthreads();

    bf16x8 afrag[2][4];
    #pragma unroll
    for (int mt = 0; mt < 2; mt++) {
        #pragma unroll
        for (int kk = 0; kk < 4; kk++) {
            int r = wave * 32 + mt * 16 + (lane & 15);
            int chunk = (kk * 4 + (lane >> 4)) ^ (r & 7);
            afrag[mt][kk] = *(const bf16x8*)(sh + r * 128 + chunk * 8);
        }
    }
    __syncthreads();   // afrags in regs; sh free for C staging

    if (cb < 8) {
        #pragma unroll
        for (int nt = 0; nt < 8; nt++) {
            int ct = cb * 8 + nt;
            const bf16x8* bp = (const bf16x8*)(wbt_frag + (((size_t)ct * 4) * 64 + lane) * 8);
            f32x4 acc0 = {0, 0, 0, 0}, acc1 = {0, 0, 0, 0};
            #pragma unroll
            for (int kk = 0; kk < 4; kk++) {
                bf16x8 bfrag = bp[kk * 64];   // coalesced: lane-contiguous 1KB
                acc0 = __builtin_amdgcn_mfma_f32_16x16x32_bf16(afrag[0][kk], bfrag, acc0, 0, 0, 0);
                acc1 = __builtin_amdgcn_mfma_f32_16x16x32_bf16(afrag[1][kk], bfrag, acc1, 0, 0, 0);
            }
            int lcol = nt * 16 + (lane & 15);
            int ch = lcol >> 3, cin = lcol & 7;
            #pragma unroll
            for (int mt = 0; mt < 2; mt++) {
                f32x4 a = (mt == 0) ? acc0 : acc1;
                int rbase = wave * 32 + mt * 16 + (lane >> 4) * 4;
                #pragma unroll
                for (int jj = 0; jj < 4; jj++) {
                    int row = rbase + jj;
                    int chs = ch ^ ((row >> 2) & 3);
                    sh[row * 128 + chs * 8 + cin] = f2bf(a[jj]);
                }
            }
        }
        __syncthreads();
        u16* out = (cb < 4) ? xl : xr;
        const int colbase = (cb & 3) * 128;
        #pragma unroll
        for (int it = 0; it < 8; it++) {
            int idx = tid + it * 256;
            int r = idx >> 4, ch = idx & 15;
            int grow = row0 + r;
            if (grow < N) {
                int chs = ch ^ ((r >> 2) & 3);
                uint4 v = *(const uint4*)(sh + r * 128 + chs * 8);
                *(uint4*)(out + (size_t)grow * HC + colbase + ch * 8) = v;
            }
        }
    } else {
        #pragma unroll
        for (int nt = 0; nt < 2; nt++) {
            int ct = 64 + nt;
            const bf16x8* bp = (const bf16x8*)(wbt_frag + (((size_t)ct * 4) * 64 + lane) * 8);
            f32x4 acc0 = {0, 0, 0, 0}, acc1 = {0, 0, 0, 0};
            #pragma unroll
            for (int kk = 0; kk < 4; kk++) {
                bf16x8 bfrag = bp[kk * 64];
                acc0 = __builtin_amdgcn_mfma_f32_16x16x32_bf16(afrag[0][kk], bfrag, acc0, 0, 0, 0);
                acc1 = __builtin_amdgcn_mfma_f32_16x16x32_bf16(afrag[1][kk], bfrag, acc1, 0, 0, 0);
            }
            int c_out = nt * 16 + (lane & 15);
            #pragma unroll
            for (int mt = 0; mt < 2; mt++) {
                f32x4 a = (mt == 0) ? acc0 : acc1;
                int rbse = row0 + wave * 32 + mt * 16 + (lane >> 4) * 4;
                #pragma unroll
                for (int jj = 0; jj < 4; jj++) {
                    int grow = rbse + jj;
                    if (grow < N) xres[(size_t)grow * CC + c_out] = a[jj];
                }
            }
        }
    }
}

// ---------- CSR build ----------
__global__ __launch_bounds__(1024) void k_scan1(
    const int* __restrict__ counts, int* __restrict__ offs, int* __restrict__ partials, int N)
{
    __shared__ int sh[1024];
    int i = blockIdx.x * 1024 + threadIdx.x;
    int v = (i < N) ? counts[i] : 0;
    sh[threadIdx.x] = v;
    __syncthreads();
    for (int off = 1; off < 1024; off <<= 1) {
        int t = (threadIdx.x >= off) ? sh[threadIdx.x - off] : 0;
        __syncthreads();
        sh[threadIdx.x] += t;
        __syncthreads();
    }
    if (i < N) offs[i] = sh[threadIdx.x] - v;   // exclusive within block
    if (threadIdx.x == 1023) partials[blockIdx.x] = sh[1023];   // raw block sum
}

// scan3 with inline exclusive-prefix of partials (nb <= 64)
__global__ __launch_bounds__(1024) void k_scan3f(
    int* __restrict__ offs, const int* __restrict__ partials,
    int* __restrict__ cursor, int N, int nb)
{
    __shared__ int sbase;
    if (threadIdx.x < 64) {
        int k = threadIdx.x;
        int v = (k < nb && k < blockIdx.x) ? partials[k] : 0;
        #pragma unroll
        for (int st = 1; st < 64; st <<= 1) v += __shfl_xor(v, st);
        if (threadIdx.x == 0) sbase = v;
    }
    __syncthreads();
    int i = blockIdx.x * 1024 + threadIdx.x;
    if (i < N) {
        int o = offs[i] + sbase;
        offs[i] = o;
        cursor[i] = o;
    }
}

__global__ __launch_bounds__(256) void k_scatter(
    const int* __restrict__ ei, int* __restrict__ cursor,
    int* __restrict__ src_sorted, int* __restrict__ eid_sorted, int E, int N)
{
    int e = blockIdx.x * 256 + threadIdx.x;
    if (e >= E + N) return;
    int src, dst;
    if (e < E) { src = ei[e]; dst = ei[E + e]; }
    else       { src = e - E; dst = src; }
    int pos = atomicAdd(&cursor[dst], 1);
    src_sorted[pos] = src;
    eid_sorted[pos] = e;
}

// ---------- K_fused: 1 workgroup (64 thr) per node, 32 lanes PER EDGE ----------
// Halves of the wave process 2 consecutive CSR edges per iteration with the
// SAME instructions/registers (edge data differs only by lane). Per-edge fixed
// cost and the serial online-softmax chain both halve; 2 gather rows in flight.
// lane l (=lane&31) covers channels [l*16, l*16+16) -> head h = l>>1.
__global__ __launch_bounds__(64) void k_fused(
    const int* __restrict__ src_sorted, const int* __restrict__ eid_sorted,
    const int* __restrict__ offs, const int* __restrict__ counts,
    const u16* __restrict__ xl, const u16* __restrict__ xr, const float* __restrict__ att,
    float* __restrict__ e_out, float2* __restrict__ ms_buf,
    float* __restrict__ out_mean, int N)
{
    const int node = blockIdx.x;
    const int lane = threadIdx.x;      // 0..63
    const int l    = lane & 31;        // channel-lane within the half
    const int half = lane >> 5;        // 0: even edge of pair, 1: odd edge
    const int h    = l >> 1;           // head

    // xr row: same channels for both halves
    const uint4* xr4 = (const uint4*)(xr + (size_t)node * HC) + l * 2;
    uint4 b0 = xr4[0], b1 = xr4[1];
    f32x2 xrv[8] = { {bflo(b0.x),bfhi(b0.x)}, {bflo(b0.y),bfhi(b0.y)},
                     {bflo(b0.z),bfhi(b0.z)}, {bflo(b0.w),bfhi(b0.w)},
                     {bflo(b1.x),bfhi(b1.x)}, {bflo(b1.y),bfhi(b1.y)},
                     {bflo(b1.z),bfhi(b1.z)}, {bflo(b1.w),bfhi(b1.w)} };
    const float4* att4 = (const float4*)att + l * 4;
    float4 w0 = att4[0], w1 = att4[1], w2 = att4[2], w3 = att4[3];
    f32x2 wv[8] = { {w0.x,w0.y},{w0.z,w0.w},{w1.x,w1.y},{w1.z,w1.w},
                    {w2.x,w2.y},{w2.z,w2.w},{w3.x,w3.y},{w3.z,w3.w} };

    float m = -3.402823466e38f, s = 0.f;
    f32x2 ac[8] = { {0,0},{0,0},{0,0},{0,0},{0,0},{0,0},{0,0},{0,0} };

    const int beg = offs[node];
    const int deg = counts[node];

    int te = min(half, deg - 1);
    {
        int sv = src_sorted[beg + te];
        const uint4* ap = (const uint4*)(xl + (size_t)sv * HC) + l * 2;
        b0 = ap[0]; b1 = ap[1];
    }
    for (int t0 = 0; t0 < deg; t0 += 2) {
        uint4 c0 = b0, c1 = b1;
        bool valid = (t0 + half) < deg;
        {   // prefetch next pair (clamped; redundant at tail)
            int sn = src_sorted[beg + min(t0 + 2 + half, deg - 1)];
            const uint4* np = (const uint4*)(xl + (size_t)sn * HC) + l * 2;
            b0 = np[0]; b1 = np[1];
        }
        f32x2 xv[8] = { {bflo(c0.x),bfhi(c0.x)}, {bflo(c0.y),bfhi(c0.y)},
                        {bflo(c0.z),bfhi(c0.z)}, {bflo(c0.w),bfhi(c0.w)},
                        {bflo(c1.x),bfhi(c1.x)}, {bflo(c1.y),bfhi(c1.y)},
                        {bflo(c1.z),bfhi(c1.z)}, {bflo(c1.w),bfhi(c1.w)} };
        f32x2 es = {0.f, 0.f};
        #pragma unroll
        for (int q = 0; q < 8; q++) {
            f32x2 v = xv[q] + xrv[q];
            v = __builtin_elementwise_max(v, 0.2f * v);     // leaky_relu
            es = __builtin_elementwise_fma(v, wv[q], es);
        }
        float esum = es.x + es.y;
        esum += __shfl_xor(esum, 1);    // pair (2h, 2h+1) completes the head dot

        int eid = eid_sorted[beg + min(t0 + half, deg - 1)];
        if ((l & 1) == 0 && valid)
            e_out[(size_t)eid * HH + h] = esum;

        if (__any(esum > m + RESCALE_THR)) {   // rare: rescale path
            float mn = fmaxf(m, esum);
            float sc = __expf(m - mn);
            float p  = __expf(esum - mn);
            if (!valid) p = 0.f;               // dead duplicate edge
            s = s * sc + p;
            m = mn;
            f32x2 p2 = {p, p}, sc2 = {sc, sc};
            #pragma unroll
            for (int q = 0; q < 8; q++)
                ac[q] = __builtin_elementwise_fma(p2, xv[q], ac[q] * sc2);
        } else {                               // common: no rescale
            float p = __expf(esum - m);
            if (!valid) p = 0.f;
            s += p;
            f32x2 p2 = {p, p};
            #pragma unroll
            for (int q = 0; q < 8; q++)
                ac[q] = __builtin_elementwise_fma(p2, xv[q], ac[q]);
        }
    }

    // ---- merge halves (online-softmax state merge across lane^32) ----
    float mo = __shfl_xor(m, 32);
    float mx = fmaxf(m, mo);
    float sc = __expf(m - mx);
    s *= sc;
    s += __shfl_xor(s, 32);
    f32x2 sc2 = {sc, sc};
    #pragma unroll
    for (int q = 0; q < 8; q++) {
        f32x2 t = ac[q] * sc2;
        t.x += __shfl_xor(t.x, 32);
        t.y += __shfl_xor(t.y, 32);
        ac[q] = t;
    }

    float inv = 1.f / (s + 1e-16f);
    if (lane < 32 && (l & 1) == 0)
        ms_buf[(size_t)node * HH + h] = make_float2(mx, inv);

    f32x2 inv2 = {inv, inv};
    #pragma unroll
    for (int q = 0; q < 8; q++) ac[q] = ac[q] * inv2;

    // head reduction: sum lanes of same parity (strides 2,4,8,16)
    #pragma unroll
    for (int st = 2; st <= 16; st <<= 1) {
        #pragma unroll
        for (int q = 0; q < 8; q++) {
            ac[q].x += __shfl_xor(ac[q].x, st);
            ac[q].y += __shfl_xor(ac[q].y, st);
        }
    }
    if (lane < 2) {   // lane 0: out cols 0..15, lane 1: cols 16..31
        float4* dp = (float4*)(out_mean + (size_t)node * CC + lane * 16);
        dp[0] = make_float4(ac[0].x, ac[0].y, ac[1].x, ac[1].y);
        dp[1] = make_float4(ac[2].x, ac[2].y, ac[3].x, ac[3].y);
        dp[2] = make_float4(ac[4].x, ac[4].y, ac[5].x, ac[5].y);
        dp[3] = make_float4(ac[6].x, ac[6].y, ac[7].x, ac[7].y);
    }
}

// ---------- K_alphafinal: fused {alpha finalize, head-mean epilogue} ----------
__global__ __launch_bounds__(256) void k_alphafinal(
    const int* __restrict__ ei, float* __restrict__ alpha,
    const float2* __restrict__ ms_buf, const float* __restrict__ out_mean,
    const float* __restrict__ xres, const float* __restrict__ bias,
    float* __restrict__ x_out, int E, int N)
{
    long long i = (long long)blockIdx.x * 256 + threadIdx.x;
    if (i < (long long)N * CC) {
        int c = (int)(i & 31);
        float g = out_mean[i] * (1.f / 16.f) + bias[c];
        g = g > 0.f ? g : 0.f;
        x_out[i] = g + xres[i];
    }
    long long tot = (long long)(E + N) * HH;
    if (i < tot) {
        int edge = (int)(i >> 4);
        int h = (int)(i & 15);
        int dst = (edge < E) ? ei[E + edge] : edge - E;
        float2 ms = ms_buf[(size_t)dst * HH + h];
        alpha[i] = __expf(alpha[i] - ms.x) * ms.y;
    }
}

extern "C" void kernel_launch(void* const* d_in, const int* in_sizes, int n_in,
                              void* d_out, int out_size, void* d_ws, size_t ws_size,
                              hipStream_t stream)
{
    const int N = in_sizes[0] / KIN;   // 50000
    const int E = in_sizes[1] / 2;     // 400000
    const int Etot = E + N;

    const float* x    = (const float*)d_in[0];
    const int*   ei   = (const int*)d_in[1];
    const float* Wl   = (const float*)d_in[4];
    const float* Wr   = (const float*)d_in[5];
    const float* att  = (const float*)d_in[6];
    const float* bias = (const float*)d_in[7];
    const float* Wres = (const float*)d_in[8];

    char* ws = (char*)d_ws;
    u16*   xl         = (u16*)ws;   ws += (size_t)N * HC * 2;
    u16*   xr         = (u16*)ws;   ws += (size_t)N * HC * 2;
    float2* ms_buf    = (float2*)ws; ws += (size_t)N * HH * 8;
    float* xres       = (float*)ws; ws += (size_t)N * CC * 4;
    float* out_mean   = (float*)ws; ws += (size_t)N * CC * 4;
    int*   counts     = (int*)ws;   ws += (size_t)N * 4;
    int*   offs       = (int*)ws;   ws += (size_t)N * 4;
    int*   cursor     = (int*)ws;   ws += (size_t)N * 4;
    int*   partials   = (int*)ws;   ws += 256;
    int*   src_sorted = (int*)ws;   ws += (size_t)Etot * 4;
    int*   eid_sorted = (int*)ws;   ws += (size_t)Etot * 4;
    u16*   xb         = (u16*)ws;   ws += (size_t)N * KIN * 2;
    u16*   wbt_frag   = (u16*)ws;   ws += (size_t)CT * KIN * 2;

    float* x_out     = (float*)d_out;
    float* alpha_out = x_out + (size_t)N * CC;

    hipMemsetAsync(counts, 0, (size_t)N * 4, stream);

    // K1: prep (xconv + wconv + edge count)
    int xq = N * KIN / 8;                       // 800000
    int ptot = xq + CT * 128 + Etot;
    k_prep<<<(ptot + 255) / 256, 256, 0, stream>>>(
        x, Wl, Wr, Wres, ei, xb, wbt_frag, counts, xq, E, N);

    // K2: MFMA GEMM (9 col-panels, LDS-staged C)
    int nrb = (N + 127) / 128;
    int mgrid = 8 * ((nrb + 7) / 8) * 9;
    k_mfma<<<mgrid, 256, 0, stream>>>(xb, wbt_frag, xl, xr, xres, N, nrb);

    // K3..K5: CSR build
    int nb = (N + 1023) / 1024;
    k_scan1<<<nb, 1024, 0, stream>>>(counts, offs, partials, N);
    k_scan3f<<<nb, 1024, 0, stream>>>(offs, partials, cursor, N, nb);
    int eg = (Etot + 255) / 256;
    k_scatter<<<eg, 256, 0, stream>>>(ei, cursor, src_sorted, eid_sorted, E, N);

    // K6: fused attention aggregate (64 thr/node, 32 lanes per edge)
    k_fused<<<N, 64, 0, stream>>>(
        src_sorted, eid_sorted, offs, counts, xl, xr, att,
        alpha_out, ms_buf, out_mean, N);

    // K7: alpha finalize + epilogue
    long long tot = (long long)Etot * HH;
    k_alphafinal<<<(int)((tot + 255) / 256), 256, 0, stream>>>(
        ei, alpha_out, ms_buf, out_mean, xres, bias, x_out, E, N);
}

// Round 13
// 191.239 us; speedup vs baseline: 1.1023x; 1.1023x over previous
//
#include <hip/hip_runtime.h>
#include <hip/hip_bf16.h>

typedef unsigned int u32;
typedef unsigned short u16;

typedef __attribute__((ext_vector_type(8))) short bf16x8;
typedef __attribute__((ext_vector_type(4))) float f32x4;
typedef __attribute__((ext_vector_type(2))) float f32x2;

// ---------- bf16 helpers ----------
__device__ __forceinline__ float bflo(u32 p){ union{u32 u; float f;} v; v.u = p << 16; return v.f; }
__device__ __forceinline__ float bfhi(u32 p){ union{u32 u; float f;} v; v.u = p & 0xFFFF0000u; return v.f; }
__device__ __forceinline__ u16 f2bf(float f){
    union{float f; u32 u;} v; v.f = f;
    u32 r = (v.u + 0x7FFFu + ((v.u >> 16) & 1u)) >> 16;
    return (u16)r;
}
__device__ __forceinline__ u32 pack2(float a, float b){
    return ((u32)f2bf(a)) | (((u32)f2bf(b)) << 16);
}

#define HH 16
#define CC 32
#define HC 512   // H*C
#define KIN 128
#define CT 1056  // 512 + 512 + 32 output cols
#define RESCALE_THR 8.0f

// ---------- K_prep: fused {x->bf16, W->frag-order bf16, edge count} ----------
// counts must be zeroed (hipMemsetAsync) before this kernel.
__global__ __launch_bounds__(256) void k_prep(
    const float* __restrict__ x, const float* __restrict__ Wl,
    const float* __restrict__ Wr, const float* __restrict__ Wres,
    const int* __restrict__ ei,
    u16* __restrict__ xb, u16* __restrict__ wbt_frag, int* __restrict__ counts,
    int xq, int E, int N)
{
    int t = blockIdx.x * 256 + threadIdx.x;
    if (t < xq) {
        const float4* src = (const float4*)(x + (size_t)t * 8);
        float4 a = src[0], b = src[1];
        uint4 o;
        o.x = pack2(a.x, a.y); o.y = pack2(a.z, a.w);
        o.z = pack2(b.x, b.y); o.w = pack2(b.z, b.w);
        ((uint4*)xb)[t] = o;
    } else if (t < xq + CT * 128) {
        int u = t - xq;
        int c = u >> 7;            // 0..1055
        int k = u & 127;           // 0..127
        float v;
        if (c < 512)       v = Wl[(size_t)k * 512 + c];
        else if (c < 1024) v = Wr[(size_t)k * 512 + (c - 512)];
        else               v = Wres[(size_t)k * 32 + (c - 1024)];
        int e    = k & 7;
        int krow = k >> 3;
        int kk   = krow >> 2;
        int lane = ((krow & 3) << 4) | (c & 15);
        int ct   = c >> 4;
        wbt_frag[(((size_t)ct * 4 + kk) * 64 + lane) * 8 + e] = f2bf(v);
    } else if (t < xq + CT * 128 + E + N) {
        int e = t - xq - CT * 128;
        int dst = (e < E) ? ei[E + e] : e - E;
        atomicAdd(&counts[dst], 1);
    }
}

// ---------- K_mfma: [M,128] x [128,1056] via mfma_f32_16x16x32_bf16 ----------
// XCD-aware grid (row-block pinned to XCD rb%8 for xb L2 reuse).
// B fragments pre-permuted -> coalesced 1KB loads. C staged via LDS.
__global__ __launch_bounds__(256) void k_mfma(
    const u16* __restrict__ xb, const u16* __restrict__ wbt_frag,
    u16* __restrict__ xl, u16* __restrict__ xr, float* __restrict__ xres,
    int N, int nrb)
{
    __shared__ u16 sh[128 * 128];   // 32 KB: A stage, then C stage
    const int i = blockIdx.x;
    const int xcd = i & 7;
    const int j = i >> 3;
    const int rb = xcd + 8 * (j / 9);
    const int cb = j % 9;
    if (rb >= nrb) return;
    const int tid = threadIdx.x;
    const int wave = tid >> 6, lane = tid & 63;
    const int row0 = rb * 128;

    uint4 zero = {0, 0, 0, 0};
    #pragma unroll
    for (int it = 0; it < 8; it++) {
        int idx = tid + it * 256;        // 0..2047
        int r = idx >> 4, ch = idx & 15;
        int grow = row0 + r;
        uint4 v = (grow < N) ? ((const uint4*)(xb + (size_t)grow * KIN))[ch] : zero;
        *(uint4*)(sh + r * 128 + ((ch ^ (r & 7)) * 8)) = v;
    }
    __syncthreads();

    bf16x8 afrag[2][4];
    #pragma unroll
    for (int mt = 0; mt < 2; mt++) {
        #pragma unroll
        for (int kk = 0; kk < 4; kk++) {
            int r = wave * 32 + mt * 16 + (lane & 15);
            int chunk = (kk * 4 + (lane >> 4)) ^ (r & 7);
            afrag[mt][kk] = *(const bf16x8*)(sh + r * 128 + chunk * 8);
        }
    }
    __syncthreads();   // afrags in regs; sh free for C staging

    if (cb < 8) {
        #pragma unroll
        for (int nt = 0; nt < 8; nt++) {
            int ct = cb * 8 + nt;
            const bf16x8* bp = (const bf16x8*)(wbt_frag + (((size_t)ct * 4) * 64 + lane) * 8);
            f32x4 acc0 = {0, 0, 0, 0}, acc1 = {0, 0, 0, 0};
            #pragma unroll
            for (int kk = 0; kk < 4; kk++) {
                bf16x8 bfrag = bp[kk * 64];   // coalesced: lane-contiguous 1KB
                acc0 = __builtin_amdgcn_mfma_f32_16x16x32_bf16(afrag[0][kk], bfrag, acc0, 0, 0, 0);
                acc1 = __builtin_amdgcn_mfma_f32_16x16x32_bf16(afrag[1][kk], bfrag, acc1, 0, 0, 0);
            }
            int lcol = nt * 16 + (lane & 15);
            int ch = lcol >> 3, cin = lcol & 7;
            #pragma unroll
            for (int mt = 0; mt < 2; mt++) {
                f32x4 a = (mt == 0) ? acc0 : acc1;
                int rbase = wave * 32 + mt * 16 + (lane >> 4) * 4;
                #pragma unroll
                for (int jj = 0; jj < 4; jj++) {
                    int row = rbase + jj;
                    int chs = ch ^ ((row >> 2) & 3);
                    sh[row * 128 + chs * 8 + cin] = f2bf(a[jj]);
                }
            }
        }
        __syncthreads();
        u16* out = (cb < 4) ? xl : xr;
        const int colbase = (cb & 3) * 128;
        #pragma unroll
        for (int it = 0; it < 8; it++) {
            int idx = tid + it * 256;
            int r = idx >> 4, ch = idx & 15;
            int grow = row0 + r;
            if (grow < N) {
                int chs = ch ^ ((r >> 2) & 3);
                uint4 v = *(const uint4*)(sh + r * 128 + chs * 8);
                *(uint4*)(out + (size_t)grow * HC + colbase + ch * 8) = v;
            }
        }
    } else {
        #pragma unroll
        for (int nt = 0; nt < 2; nt++) {
            int ct = 64 + nt;
            const bf16x8* bp = (const bf16x8*)(wbt_frag + (((size_t)ct * 4) * 64 + lane) * 8);
            f32x4 acc0 = {0, 0, 0, 0}, acc1 = {0, 0, 0, 0};
            #pragma unroll
            for (int kk = 0; kk < 4; kk++) {
                bf16x8 bfrag = bp[kk * 64];
                acc0 = __builtin_amdgcn_mfma_f32_16x16x32_bf16(afrag[0][kk], bfrag, acc0, 0, 0, 0);
                acc1 = __builtin_amdgcn_mfma_f32_16x16x32_bf16(afrag[1][kk], bfrag, acc1, 0, 0, 0);
            }
            int c_out = nt * 16 + (lane & 15);
            #pragma unroll
            for (int mt = 0; mt < 2; mt++) {
                f32x4 a = (mt == 0) ? acc0 : acc1;
                int rbse = row0 + wave * 32 + mt * 16 + (lane >> 4) * 4;
                #pragma unroll
                for (int jj = 0; jj < 4; jj++) {
                    int grow = rbse + jj;
                    if (grow < N) xres[(size_t)grow * CC + c_out] = a[jj];
                }
            }
        }
    }
}

// ---------- CSR build ----------
__global__ __launch_bounds__(1024) void k_scan1(
    const int* __restrict__ counts, int* __restrict__ offs, int* __restrict__ partials, int N)
{
    __shared__ int sh[1024];
    int i = blockIdx.x * 1024 + threadIdx.x;
    int v = (i < N) ? counts[i] : 0;
    sh[threadIdx.x] = v;
    __syncthreads();
    for (int off = 1; off < 1024; off <<= 1) {
        int t = (threadIdx.x >= off) ? sh[threadIdx.x - off] : 0;
        __syncthreads();
        sh[threadIdx.x] += t;
        __syncthreads();
    }
    if (i < N) offs[i] = sh[threadIdx.x] - v;   // exclusive within block
    if (threadIdx.x == 1023) partials[blockIdx.x] = sh[1023];   // raw block sum
}

// scan3 with inline exclusive-prefix of partials (nb <= 64)
__global__ __launch_bounds__(1024) void k_scan3f(
    int* __restrict__ offs, const int* __restrict__ partials,
    int* __restrict__ cursor, int N, int nb)
{
    __shared__ int sbase;
    if (threadIdx.x < 64) {
        int k = threadIdx.x;
        int v = (k < nb && k < blockIdx.x) ? partials[k] : 0;
        #pragma unroll
        for (int st = 1; st < 64; st <<= 1) v += __shfl_xor(v, st);
        if (threadIdx.x == 0) sbase = v;
    }
    __syncthreads();
    int i = blockIdx.x * 1024 + threadIdx.x;
    if (i < N) {
        int o = offs[i] + sbase;
        offs[i] = o;
        cursor[i] = o;
    }
}

// ---------- K_scatter: one packed int2 {src, eid} per position ----------
__global__ __launch_bounds__(256) void k_scatter(
    const int* __restrict__ ei, int* __restrict__ cursor,
    int2* __restrict__ se_sorted, int E, int N)
{
    int e = blockIdx.x * 256 + threadIdx.x;
    if (e >= E + N) return;
    int src, dst;
    if (e < E) { src = ei[e]; dst = ei[E + e]; }
    else       { src = e - E; dst = src; }
    int pos = atomicAdd(&cursor[dst], 1);
    se_sorted[pos] = make_int2(src, e);
}

// ---------- K_fused: one 64-thread workgroup per node ----------
// blockIdx = node -> all CSR/index reads are wave-uniform (scalar pipe).
// Channel math in packed f32x2 (v_pk_* on gfx950).
__global__ __launch_bounds__(64) void k_fused(
    const int2* __restrict__ se_sorted,
    const int* __restrict__ offs, const int* __restrict__ counts,
    const u16* __restrict__ xl, const u16* __restrict__ xr, const float* __restrict__ att,
    float* __restrict__ e_out, float2* __restrict__ ms_buf,
    float* __restrict__ out_mean, int N)
{
    const int node = blockIdx.x;
    const int lane = threadIdx.x;          // 0..63
    const int h = lane >> 2;

    uint4 b = ((const uint4*)(xr + (size_t)node * HC))[lane];
    f32x2 xr0 = {bflo(b.x), bfhi(b.x)}, xr1 = {bflo(b.y), bfhi(b.y)};
    f32x2 xr2 = {bflo(b.z), bfhi(b.z)}, xr3 = {bflo(b.w), bfhi(b.w)};
    float4 w0 = ((const float4*)att)[lane * 2];
    float4 w1 = ((const float4*)att)[lane * 2 + 1];
    f32x2 wv0 = {w0.x, w0.y}, wv1 = {w0.z, w0.w};
    f32x2 wv2 = {w1.x, w1.y}, wv3 = {w1.z, w1.w};

    float m = -3.402823466e38f, s = 0.f;
    f32x2 ac0 = {0,0}, ac1 = {0,0}, ac2 = {0,0}, ac3 = {0,0};

    const int beg = offs[node];
    const int deg = counts[node];

    int2 se = se_sorted[beg];                       // uniform -> scalar
    uint4 a = ((const uint4*)(xl + (size_t)se.x * HC))[lane];
    for (int t = 0; t < deg; t++) {
        uint4 acr = a;
        int eid = se.y;
        {   // unconditional clamped prefetch (redundant on last iter)
            se = se_sorted[beg + min(t + 1, deg - 1)];
            a = ((const uint4*)(xl + (size_t)se.x * HC))[lane];
        }

        f32x2 xv0 = {bflo(acr.x), bfhi(acr.x)};
        f32x2 xv1 = {bflo(acr.y), bfhi(acr.y)};
        f32x2 xv2 = {bflo(acr.z), bfhi(acr.z)};
        f32x2 xv3 = {bflo(acr.w), bfhi(acr.w)};

        f32x2 es2 = {0.f, 0.f};
        f32x2 v;
        v = xv0 + xr0; v = __builtin_elementwise_max(v, 0.2f * v); es2 = __builtin_elementwise_fma(v, wv0, es2);
        v = xv1 + xr1; v = __builtin_elementwise_max(v, 0.2f * v); es2 = __builtin_elementwise_fma(v, wv1, es2);
        v = xv2 + xr2; v = __builtin_elementwise_max(v, 0.2f * v); es2 = __builtin_elementwise_fma(v, wv2, es2);
        v = xv3 + xr3; v = __builtin_elementwise_max(v, 0.2f * v); es2 = __builtin_elementwise_fma(v, wv3, es2);
        float esum = es2.x + es2.y;
        esum += __shfl_xor(esum, 1);
        esum += __shfl_xor(esum, 2);     // 4 lanes of head group hold e

        if ((lane & 3) == 0)
            e_out[(size_t)eid * HH + h] = esum;

        if (__any(esum > m + RESCALE_THR)) {   // rare: rescale
            float mn = fmaxf(m, esum);
            float sc = __expf(m - mn);
            float p  = __expf(esum - mn);
            s = s * sc + p;
            m = mn;
            f32x2 p2 = {p, p}, sc2 = {sc, sc};
            ac0 = __builtin_elementwise_fma(p2, xv0, ac0 * sc2);
            ac1 = __builtin_elementwise_fma(p2, xv1, ac1 * sc2);
            ac2 = __builtin_elementwise_fma(p2, xv2, ac2 * sc2);
            ac3 = __builtin_elementwise_fma(p2, xv3, ac3 * sc2);
        } else {                               // common
            float p = __expf(esum - m);
            s += p;
            f32x2 p2 = {p, p};
            ac0 = __builtin_elementwise_fma(p2, xv0, ac0);
            ac1 = __builtin_elementwise_fma(p2, xv1, ac1);
            ac2 = __builtin_elementwise_fma(p2, xv2, ac2);
            ac3 = __builtin_elementwise_fma(p2, xv3, ac3);
        }
    }

    float inv = 1.f / (s + 1e-16f);
    if ((lane & 3) == 0)
        ms_buf[(size_t)node * HH + h] = make_float2(m, inv);

    float acc[8] = { ac0.x * inv, ac0.y * inv, ac1.x * inv, ac1.y * inv,
                     ac2.x * inv, ac2.y * inv, ac3.x * inv, ac3.y * inv };
    #pragma unroll
    for (int st = 4; st <= 32; st <<= 1) {
        #pragma unroll
        for (int q = 0; q < 8; q++) acc[q] += __shfl_xor(acc[q], st);
    }
    if (lane < 4) {
        float* dp = out_mean + (size_t)node * CC + lane * 8;
        #pragma unroll
        for (int q = 0; q < 8; q++) dp[q] = acc[q];
    }
}

// ---------- K_alphafinal: fused {alpha finalize, head-mean epilogue} ----------
__global__ __launch_bounds__(256) void k_alphafinal(
    const int* __restrict__ ei, float* __restrict__ alpha,
    const float2* __restrict__ ms_buf, const float* __restrict__ out_mean,
    const float* __restrict__ xres, const float* __restrict__ bias,
    float* __restrict__ x_out, int E, int N)
{
    long long i = (long long)blockIdx.x * 256 + threadIdx.x;
    if (i < (long long)N * CC) {
        int c = (int)(i & 31);
        float g = out_mean[i] * (1.f / 16.f) + bias[c];
        g = g > 0.f ? g : 0.f;
        x_out[i] = g + xres[i];
    }
    long long tot = (long long)(E + N) * HH;
    if (i < tot) {
        int edge = (int)(i >> 4);
        int h = (int)(i & 15);
        int dst = (edge < E) ? ei[E + edge] : edge - E;
        float2 ms = ms_buf[(size_t)dst * HH + h];
        alpha[i] = __expf(alpha[i] - ms.x) * ms.y;
    }
}

extern "C" void kernel_launch(void* const* d_in, const int* in_sizes, int n_in,
                              void* d_out, int out_size, void* d_ws, size_t ws_size,
                              hipStream_t stream)
{
    const int N = in_sizes[0] / KIN;   // 50000
    const int E = in_sizes[1] / 2;     // 400000
    const int Etot = E + N;

    const float* x    = (const float*)d_in[0];
    const int*   ei   = (const int*)d_in[1];
    const float* Wl   = (const float*)d_in[4];
    const float* Wr   = (const float*)d_in[5];
    const float* att  = (const float*)d_in[6];
    const float* bias = (const float*)d_in[7];
    const float* Wres = (const float*)d_in[8];

    char* ws = (char*)d_ws;
    u16*   xl         = (u16*)ws;   ws += (size_t)N * HC * 2;
    u16*   xr         = (u16*)ws;   ws += (size_t)N * HC * 2;
    float2* ms_buf    = (float2*)ws; ws += (size_t)N * HH * 8;
    float* xres       = (float*)ws; ws += (size_t)N * CC * 4;
    float* out_mean   = (float*)ws; ws += (size_t)N * CC * 4;
    int*   counts     = (int*)ws;   ws += (size_t)N * 4;
    int*   offs       = (int*)ws;   ws += (size_t)N * 4;
    int*   cursor     = (int*)ws;   ws += (size_t)N * 4;
    int*   partials   = (int*)ws;   ws += 256;
    int2*  se_sorted  = (int2*)ws;  ws += (size_t)Etot * 8;
    u16*   xb         = (u16*)ws;   ws += (size_t)N * KIN * 2;
    u16*   wbt_frag   = (u16*)ws;   ws += (size_t)CT * KIN * 2;

    float* x_out     = (float*)d_out;
    float* alpha_out = x_out + (size_t)N * CC;

    hipMemsetAsync(counts, 0, (size_t)N * 4, stream);

    // K1: prep (xconv + wconv + edge count)
    int xq = N * KIN / 8;                       // 800000
    int ptot = xq + CT * 128 + Etot;
    k_prep<<<(ptot + 255) / 256, 256, 0, stream>>>(
        x, Wl, Wr, Wres, ei, xb, wbt_frag, counts, xq, E, N);

    // K2: MFMA GEMM (9 col-panels, LDS-staged C)
    int nrb = (N + 127) / 128;
    int mgrid = 8 * ((nrb + 7) / 8) * 9;
    k_mfma<<<mgrid, 256, 0, stream>>>(xb, wbt_frag, xl, xr, xres, N, nrb);

    // K3..K5: CSR build
    int nb = (N + 1023) / 1024;
    k_scan1<<<nb, 1024, 0, stream>>>(counts, offs, partials, N);
    k_scan3f<<<nb, 1024, 0, stream>>>(offs, partials, cursor, N, nb);
    int eg = (Etot + 255) / 256;
    k_scatter<<<eg, 256, 0, stream>>>(ei, cursor, se_sorted, E, N);

    // K6: fused attention aggregate (1 wave/node workgroups)
    k_fused<<<N, 64, 0, stream>>>(
        se_sorted, offs, counts, xl, xr, att,
        alpha_out, ms_buf, out_mean, N);

    // K7: alpha finalize + epilogue
    long long tot = (long long)Etot * HH;
    k_alphafinal<<<(int)((tot + 255) / 256), 256, 0, stream>>>(
        ei, alpha_out, ms_buf, out_mean, xres, bias, x_out, E, N);
}

// Round 14
// 190.141 us; speedup vs baseline: 1.1087x; 1.0058x over previous
//
#include <hip/hip_runtime.h>
#include <hip/hip_bf16.h>

typedef unsigned int u32;
typedef unsigned short u16;

typedef __attribute__((ext_vector_type(8))) short bf16x8;
typedef __attribute__((ext_vector_type(4))) float f32x4;
typedef __attribute__((ext_vector_type(2))) float f32x2;

// ---------- bf16 helpers ----------
__device__ __forceinline__ float bflo(u32 p){ union{u32 u; float f;} v; v.u = p << 16; return v.f; }
__device__ __forceinline__ float bfhi(u32 p){ union{u32 u; float f;} v; v.u = p & 0xFFFF0000u; return v.f; }
__device__ __forceinline__ u16 f2bf(float f){
    union{float f; u32 u;} v; v.f = f;
    u32 r = (v.u + 0x7FFFu + ((v.u >> 16) & 1u)) >> 16;
    return (u16)r;
}
__device__ __forceinline__ u32 pack2(float a, float b){
    return ((u32)f2bf(a)) | (((u32)f2bf(b)) << 16);
}

#define HH 16
#define CC 32
#define HC 512   // H*C
#define KIN 128
#define CT 1056  // 512 + 512 + 32 output cols
#define RESCALE_THR 8.0f

// ---------- K_prep: fused {x->bf16, W->frag-order bf16, edge count} ----------
// counts must be zeroed (hipMemsetAsync) before this kernel.
__global__ __launch_bounds__(256) void k_prep(
    const float* __restrict__ x, const float* __restrict__ Wl,
    const float* __restrict__ Wr, const float* __restrict__ Wres,
    const int* __restrict__ ei,
    u16* __restrict__ xb, u16* __restrict__ wbt_frag, int* __restrict__ counts,
    int xq, int E, int N)
{
    int t = blockIdx.x * 256 + threadIdx.x;
    if (t < xq) {
        const float4* src = (const float4*)(x + (size_t)t * 8);
        float4 a = src[0], b = src[1];
        uint4 o;
        o.x = pack2(a.x, a.y); o.y = pack2(a.z, a.w);
        o.z = pack2(b.x, b.y); o.w = pack2(b.z, b.w);
        ((uint4*)xb)[t] = o;
    } else if (t < xq + CT * 128) {
        int u = t - xq;
        int c = u >> 7;            // 0..1055
        int k = u & 127;           // 0..127
        float v;
        if (c < 512)       v = Wl[(size_t)k * 512 + c];
        else if (c < 1024) v = Wr[(size_t)k * 512 + (c - 512)];
        else               v = Wres[(size_t)k * 32 + (c - 1024)];
        int e    = k & 7;
        int krow = k >> 3;
        int kk   = krow >> 2;
        int lane = ((krow & 3) << 4) | (c & 15);
        int ct   = c >> 4;
        wbt_frag[(((size_t)ct * 4 + kk) * 64 + lane) * 8 + e] = f2bf(v);
    } else if (t < xq + CT * 128 + E + N) {
        int e = t - xq - CT * 128;
        int dst = (e < E) ? ei[E + e] : e - E;
        atomicAdd(&counts[dst], 1);
    }
}

// ---------- K_mfma: [M,128] x [128,1056] via mfma_f32_16x16x32_bf16 ----------
// XCD-aware grid (row-block pinned to XCD rb%8 for xb L2 reuse).
// B fragments pre-permuted -> coalesced 1KB loads. C staged via LDS.
__global__ __launch_bounds__(256) void k_mfma(
    const u16* __restrict__ xb, const u16* __restrict__ wbt_frag,
    u16* __restrict__ xl, u16* __restrict__ xr, float* __restrict__ xres,
    int N, int nrb)
{
    __shared__ u16 sh[128 * 128];   // 32 KB: A stage, then C stage
    const int i = blockIdx.x;
    const int xcd = i & 7;
    const int j = i >> 3;
    const int rb = xcd + 8 * (j / 9);
    const int cb = j % 9;
    if (rb >= nrb) return;
    const int tid = threadIdx.x;
    const int wave = tid >> 6, lane = tid & 63;
    const int row0 = rb * 128;

    uint4 zero = {0, 0, 0, 0};
    #pragma unroll
    for (int it = 0; it < 8; it++) {
        int idx = tid + it * 256;        // 0..2047
        int r = idx >> 4, ch = idx & 15;
        int grow = row0 + r;
        uint4 v = (grow < N) ? ((const uint4*)(xb + (size_t)grow * KIN))[ch] : zero;
        *(uint4*)(sh + r * 128 + ((ch ^ (r & 7)) * 8)) = v;
    }
    __syncthreads();

    bf16x8 afrag[2][4];
    #pragma unroll
    for (int mt = 0; mt < 2; mt++) {
        #pragma unroll
        for (int kk = 0; kk < 4; kk++) {
            int r = wave * 32 + mt * 16 + (lane & 15);
            int chunk = (kk * 4 + (lane >> 4)) ^ (r & 7);
            afrag[mt][kk] = *(const bf16x8*)(sh + r * 128 + chunk * 8);
        }
    }
    __syncthreads();   // afrags in regs; sh free for C staging

    if (cb < 8) {
        #pragma unroll
        for (int nt = 0; nt < 8; nt++) {
            int ct = cb * 8 + nt;
            const bf16x8* bp = (const bf16x8*)(wbt_frag + (((size_t)ct * 4) * 64 + lane) * 8);
            f32x4 acc0 = {0, 0, 0, 0}, acc1 = {0, 0, 0, 0};
            #pragma unroll
            for (int kk = 0; kk < 4; kk++) {
                bf16x8 bfrag = bp[kk * 64];   // coalesced: lane-contiguous 1KB
                acc0 = __builtin_amdgcn_mfma_f32_16x16x32_bf16(afrag[0][kk], bfrag, acc0, 0, 0, 0);
                acc1 = __builtin_amdgcn_mfma_f32_16x16x32_bf16(afrag[1][kk], bfrag, acc1, 0, 0, 0);
            }
            int lcol = nt * 16 + (lane & 15);
            int ch = lcol >> 3, cin = lcol & 7;
            #pragma unroll
            for (int mt = 0; mt < 2; mt++) {
                f32x4 a = (mt == 0) ? acc0 : acc1;
                int rbase = wave * 32 + mt * 16 + (lane >> 4) * 4;
                #pragma unroll
                for (int jj = 0; jj < 4; jj++) {
                    int row = rbase + jj;
                    int chs = ch ^ ((row >> 2) & 3);
                    sh[row * 128 + chs * 8 + cin] = f2bf(a[jj]);
                }
            }
        }
        __syncthreads();
        u16* out = (cb < 4) ? xl : xr;
        const int colbase = (cb & 3) * 128;
        #pragma unroll
        for (int it = 0; it < 8; it++) {
            int idx = tid + it * 256;
            int r = idx >> 4, ch = idx & 15;
            int grow = row0 + r;
            if (grow < N) {
                int chs = ch ^ ((r >> 2) & 3);
                uint4 v = *(const uint4*)(sh + r * 128 + chs * 8);
                *(uint4*)(out + (size_t)grow * HC + colbase + ch * 8) = v;
            }
        }
    } else {
        #pragma unroll
        for (int nt = 0; nt < 2; nt++) {
            int ct = 64 + nt;
            const bf16x8* bp = (const bf16x8*)(wbt_frag + (((size_t)ct * 4) * 64 + lane) * 8);
            f32x4 acc0 = {0, 0, 0, 0}, acc1 = {0, 0, 0, 0};
            #pragma unroll
            for (int kk = 0; kk < 4; kk++) {
                bf16x8 bfrag = bp[kk * 64];
                acc0 = __builtin_amdgcn_mfma_f32_16x16x32_bf16(afrag[0][kk], bfrag, acc0, 0, 0, 0);
                acc1 = __builtin_amdgcn_mfma_f32_16x16x32_bf16(afrag[1][kk], bfrag, acc1, 0, 0, 0);
            }
            int c_out = nt * 16 + (lane & 15);
            #pragma unroll
            for (int mt = 0; mt < 2; mt++) {
                f32x4 a = (mt == 0) ? acc0 : acc1;
                int rbse = row0 + wave * 32 + mt * 16 + (lane >> 4) * 4;
                #pragma unroll
                for (int jj = 0; jj < 4; jj++) {
                    int grow = rbse + jj;
                    if (grow < N) xres[(size_t)grow * CC + c_out] = a[jj];
                }
            }
        }
    }
}

// ---------- CSR build ----------
__global__ __launch_bounds__(1024) void k_scan1(
    const int* __restrict__ counts, int* __restrict__ offs, int* __restrict__ partials, int N)
{
    __shared__ int sh[1024];
    int i = blockIdx.x * 1024 + threadIdx.x;
    int v = (i < N) ? counts[i] : 0;
    sh[threadIdx.x] = v;
    __syncthreads();
    for (int off = 1; off < 1024; off <<= 1) {
        int t = (threadIdx.x >= off) ? sh[threadIdx.x - off] : 0;
        __syncthreads();
        sh[threadIdx.x] += t;
        __syncthreads();
    }
    if (i < N) offs[i] = sh[threadIdx.x] - v;   // exclusive within block
    if (threadIdx.x == 1023) partials[blockIdx.x] = sh[1023];   // raw block sum
}

// scan3 with inline exclusive-prefix of partials (nb <= 64)
__global__ __launch_bounds__(1024) void k_scan3f(
    int* __restrict__ offs, const int* __restrict__ partials,
    int* __restrict__ cursor, int N, int nb)
{
    __shared__ int sbase;
    if (threadIdx.x < 64) {
        int k = threadIdx.x;
        int v = (k < nb && k < blockIdx.x) ? partials[k] : 0;
        #pragma unroll
        for (int st = 1; st < 64; st <<= 1) v += __shfl_xor(v, st);
        if (threadIdx.x == 0) sbase = v;
    }
    __syncthreads();
    int i = blockIdx.x * 1024 + threadIdx.x;
    if (i < N) {
        int o = offs[i] + sbase;
        offs[i] = o;
        cursor[i] = o;
    }
}

// ---------- K_scatter: one packed int2 {src, eid} per position ----------
__global__ __launch_bounds__(256) void k_scatter(
    const int* __restrict__ ei, int* __restrict__ cursor,
    int2* __restrict__ se_sorted, int E, int N)
{
    int e = blockIdx.x * 256 + threadIdx.x;
    if (e >= E + N) return;
    int src, dst;
    if (e < E) { src = ei[e]; dst = ei[E + e]; }
    else       { src = e - E; dst = src; }
    int pos = atomicAdd(&cursor[dst], 1);
    se_sorted[pos] = make_int2(src, e);
}

// ---------- K_fused: 4 nodes per 256-thread block, 1 wave per node ----------
// Wave w handles node blockIdx*4+w (readfirstlane keeps it provably wave-
// uniform -> CSR index reads stay on the scalar pipe). Escapes the per-CU
// workgroup cap that limited 1-wave workgroups to ~73% occupancy.
__global__ __launch_bounds__(256) void k_fused(
    const int2* __restrict__ se_sorted,
    const int* __restrict__ offs, const int* __restrict__ counts,
    const u16* __restrict__ xl, const u16* __restrict__ xr, const float* __restrict__ att,
    float* __restrict__ e_out, float2* __restrict__ ms_buf,
    float* __restrict__ out_mean, int N)
{
    const int wv   = __builtin_amdgcn_readfirstlane(threadIdx.x >> 6);
    const int node = blockIdx.x * 4 + wv;
    if (node >= N) return;
    const int lane = threadIdx.x & 63;
    const int h = lane >> 2;

    uint4 b = ((const uint4*)(xr + (size_t)node * HC))[lane];
    f32x2 xr0 = {bflo(b.x), bfhi(b.x)}, xr1 = {bflo(b.y), bfhi(b.y)};
    f32x2 xr2 = {bflo(b.z), bfhi(b.z)}, xr3 = {bflo(b.w), bfhi(b.w)};
    float4 w0 = ((const float4*)att)[lane * 2];
    float4 w1 = ((const float4*)att)[lane * 2 + 1];
    f32x2 wv0 = {w0.x, w0.y}, wv1 = {w0.z, w0.w};
    f32x2 wv2 = {w1.x, w1.y}, wv3 = {w1.z, w1.w};

    float m = -3.402823466e38f, s = 0.f;
    f32x2 ac0 = {0,0}, ac1 = {0,0}, ac2 = {0,0}, ac3 = {0,0};

    const int beg = offs[node];
    const int deg = counts[node];

    int2 se = se_sorted[beg];                       // uniform -> scalar
    uint4 a = ((const uint4*)(xl + (size_t)se.x * HC))[lane];
    for (int t = 0; t < deg; t++) {
        uint4 acr = a;
        int eid = se.y;
        {   // unconditional clamped prefetch (redundant on last iter)
            se = se_sorted[beg + min(t + 1, deg - 1)];
            a = ((const uint4*)(xl + (size_t)se.x * HC))[lane];
        }

        f32x2 xv0 = {bflo(acr.x), bfhi(acr.x)};
        f32x2 xv1 = {bflo(acr.y), bfhi(acr.y)};
        f32x2 xv2 = {bflo(acr.z), bfhi(acr.z)};
        f32x2 xv3 = {bflo(acr.w), bfhi(acr.w)};

        f32x2 es2 = {0.f, 0.f};
        f32x2 v;
        v = xv0 + xr0; v = __builtin_elementwise_max(v, 0.2f * v); es2 = __builtin_elementwise_fma(v, wv0, es2);
        v = xv1 + xr1; v = __builtin_elementwise_max(v, 0.2f * v); es2 = __builtin_elementwise_fma(v, wv1, es2);
        v = xv2 + xr2; v = __builtin_elementwise_max(v, 0.2f * v); es2 = __builtin_elementwise_fma(v, wv2, es2);
        v = xv3 + xr3; v = __builtin_elementwise_max(v, 0.2f * v); es2 = __builtin_elementwise_fma(v, wv3, es2);
        float esum = es2.x + es2.y;
        esum += __shfl_xor(esum, 1);
        esum += __shfl_xor(esum, 2);     // 4 lanes of head group hold e

        if ((lane & 3) == 0)
            e_out[(size_t)eid * HH + h] = esum;

        if (__any(esum > m + RESCALE_THR)) {   // rare: rescale
            float mn = fmaxf(m, esum);
            float sc = __expf(m - mn);
            float p  = __expf(esum - mn);
            s = s * sc + p;
            m = mn;
            f32x2 p2 = {p, p}, sc2 = {sc, sc};
            ac0 = __builtin_elementwise_fma(p2, xv0, ac0 * sc2);
            ac1 = __builtin_elementwise_fma(p2, xv1, ac1 * sc2);
            ac2 = __builtin_elementwise_fma(p2, xv2, ac2 * sc2);
            ac3 = __builtin_elementwise_fma(p2, xv3, ac3 * sc2);
        } else {                               // common
            float p = __expf(esum - m);
            s += p;
            f32x2 p2 = {p, p};
            ac0 = __builtin_elementwise_fma(p2, xv0, ac0);
            ac1 = __builtin_elementwise_fma(p2, xv1, ac1);
            ac2 = __builtin_elementwise_fma(p2, xv2, ac2);
            ac3 = __builtin_elementwise_fma(p2, xv3, ac3);
        }
    }

    float inv = 1.f / (s + 1e-16f);
    if ((lane & 3) == 0)
        ms_buf[(size_t)node * HH + h] = make_float2(m, inv);

    float acc[8] = { ac0.x * inv, ac0.y * inv, ac1.x * inv, ac1.y * inv,
                     ac2.x * inv, ac2.y * inv, ac3.x * inv, ac3.y * inv };
    #pragma unroll
    for (int st = 4; st <= 32; st <<= 1) {
        #pragma unroll
        for (int q = 0; q < 8; q++) acc[q] += __shfl_xor(acc[q], st);
    }
    if (lane < 4) {
        float* dp = out_mean + (size_t)node * CC + lane * 8;
        #pragma unroll
        for (int q = 0; q < 8; q++) dp[q] = acc[q];
    }
}

// ---------- K_alphafinal: fused {alpha finalize, head-mean epilogue} ----------
__global__ __launch_bounds__(256) void k_alphafinal(
    const int* __restrict__ ei, float* __restrict__ alpha,
    const float2* __restrict__ ms_buf, const float* __restrict__ out_mean,
    const float* __restrict__ xres, const float* __restrict__ bias,
    float* __restrict__ x_out, int E, int N)
{
    long long i = (long long)blockIdx.x * 256 + threadIdx.x;
    if (i < (long long)N * CC) {
        int c = (int)(i & 31);
        float g = out_mean[i] * (1.f / 16.f) + bias[c];
        g = g > 0.f ? g : 0.f;
        x_out[i] = g + xres[i];
    }
    long long tot = (long long)(E + N) * HH;
    if (i < tot) {
        int edge = (int)(i >> 4);
        int h = (int)(i & 15);
        int dst = (edge < E) ? ei[E + edge] : edge - E;
        float2 ms = ms_buf[(size_t)dst * HH + h];
        alpha[i] = __expf(alpha[i] - ms.x) * ms.y;
    }
}

extern "C" void kernel_launch(void* const* d_in, const int* in_sizes, int n_in,
                              void* d_out, int out_size, void* d_ws, size_t ws_size,
                              hipStream_t stream)
{
    const int N = in_sizes[0] / KIN;   // 50000
    const int E = in_sizes[1] / 2;     // 400000
    const int Etot = E + N;

    const float* x    = (const float*)d_in[0];
    const int*   ei   = (const int*)d_in[1];
    const float* Wl   = (const float*)d_in[4];
    const float* Wr   = (const float*)d_in[5];
    const float* att  = (const float*)d_in[6];
    const float* bias = (const float*)d_in[7];
    const float* Wres = (const float*)d_in[8];

    char* ws = (char*)d_ws;
    u16*   xl         = (u16*)ws;   ws += (size_t)N * HC * 2;
    u16*   xr         = (u16*)ws;   ws += (size_t)N * HC * 2;
    float2* ms_buf    = (float2*)ws; ws += (size_t)N * HH * 8;
    float* xres       = (float*)ws; ws += (size_t)N * CC * 4;
    float* out_mean   = (float*)ws; ws += (size_t)N * CC * 4;
    int*   counts     = (int*)ws;   ws += (size_t)N * 4;
    int*   offs       = (int*)ws;   ws += (size_t)N * 4;
    int*   cursor     = (int*)ws;   ws += (size_t)N * 4;
    int*   partials   = (int*)ws;   ws += 256;
    int2*  se_sorted  = (int2*)ws;  ws += (size_t)Etot * 8;
    u16*   xb         = (u16*)ws;   ws += (size_t)N * KIN * 2;
    u16*   wbt_frag   = (u16*)ws;   ws += (size_t)CT * KIN * 2;

    float* x_out     = (float*)d_out;
    float* alpha_out = x_out + (size_t)N * CC;

    hipMemsetAsync(counts, 0, (size_t)N * 4, stream);

    // K1: prep (xconv + wconv + edge count)
    int xq = N * KIN / 8;                       // 800000
    int ptot = xq + CT * 128 + Etot;
    k_prep<<<(ptot + 255) / 256, 256, 0, stream>>>(
        x, Wl, Wr, Wres, ei, xb, wbt_frag, counts, xq, E, N);

    // K2: MFMA GEMM (9 col-panels, LDS-staged C)
    int nrb = (N + 127) / 128;
    int mgrid = 8 * ((nrb + 7) / 8) * 9;
    k_mfma<<<mgrid, 256, 0, stream>>>(xb, wbt_frag, xl, xr, xres, N, nrb);

    // K3..K5: CSR build
    int nb = (N + 1023) / 1024;
    k_scan1<<<nb, 1024, 0, stream>>>(counts, offs, partials, N);
    k_scan3f<<<nb, 1024, 0, stream>>>(offs, partials, cursor, N, nb);
    int eg = (Etot + 255) / 256;
    k_scatter<<<eg, 256, 0, stream>>>(ei, cursor, se_sorted, E, N);

    // K6: fused attention aggregate (4 nodes per 256-thread block)
    k_fused<<<(N + 3) / 4, 256, 0, stream>>>(
        se_sorted, offs, counts, xl, xr, att,
        alpha_out, ms_buf, out_mean, N);

    // K7: alpha finalize + epilogue
    long long tot = (long long)Etot * HH;
    k_alphafinal<<<(int)((tot + 255) / 256), 256, 0, stream>>>(
        ei, alpha_out, ms_buf, out_mean, xres, bias, x_out, E, N);
}